// Round 4
// baseline (498.619 us; speedup 1.0000x reference)
//
#include <hip/hip_runtime.h>
#include <hip/hip_bf16.h>

typedef __hip_bfloat16 bf16;
typedef float f32x4 __attribute__((ext_vector_type(4)));
typedef short s16x8 __attribute__((ext_vector_type(8)));

#define NPIX 3136   // 56*56
#define HDIM 56
#define CDIM 256

static __device__ __forceinline__ float b2f(bf16 v){ return __bfloat162float(v); }
static __device__ __forceinline__ bf16  f2b(float v){ return __float2bfloat16(v); }

// ---- fold region float offsets ----
#define O_KE_S 0
#define O_KE_B 256
#define O_E1_S 512
#define O_E1_B 640
#define O_C1_S 768
#define O_C1_B 1024
#define O_B2_S 1280
#define O_B2_B 1536
#define O_S1_S 1792
#define O_S1_B 1920
#define O_E2B  2048
#define O_GNS  2336   // gnsum[b][grp][2] : 16*32*2 = 1024 floats
#define O_GAP  3360
#define O_ATT  7456

// ================= prep: weight converts + BN folds + zeros, one kernel =========
__global__ void prep(
    const float* __restrict__ kew, const float* __restrict__ e1w,
    const float* __restrict__ e2w, const float* __restrict__ c1w,
    const float* keg, const float* keb, const float* kem, const float* kev,
    const float* e1g, const float* e1b, const float* e1m, const float* e1v,
    const float* e2b,
    const float* c1g, const float* c1b, const float* c1m, const float* c1v,
    const float* b2g, const float* b2b, const float* b2m, const float* b2v,
    const float* s1g, const float* s1bb, const float* s1m, const float* s1v,
    bf16* kewT, bf16* e1wb, bf16* e2wb, bf16* c1wb, float* o)
{
    int bid = blockIdx.x, t = threadIdx.x;
    if (bid < 576) {                       // kewT: (256,64,3,3) -> [g][tap][co_l][ci]
        int i = bid * 256 + t;
        int ci = i & 63, co_l = (i >> 6) & 63;
        int gt = i >> 12;
        int tap = gt % 9, g = gt / 9;
        int co = g * 64 + co_l;
        kewT[i] = f2b(kew[(co * 64 + ci) * 9 + tap]);
    } else if (bid < 832) {
        int i = (bid - 576) * 256 + t; e1wb[i] = f2b(e1w[i]);
    } else if (bid < 976) {
        int i = (bid - 832) * 256 + t; e2wb[i] = f2b(e2w[i]);
    } else if (bid < 1232) {
        int i = (bid - 976) * 256 + t; c1wb[i] = f2b(c1w[i]);
    } else if (bid == 1232) {
        const float eps = 1e-5f;
        {
            float s = keg[t] * rsqrtf(kev[t] + eps);
            o[O_KE_S + t] = s; o[O_KE_B + t] = keb[t] - kem[t] * s;
            s = c1g[t] * rsqrtf(c1v[t] + eps);
            o[O_C1_S + t] = s; o[O_C1_B + t] = c1b[t] - c1m[t] * s;
            s = b2g[t] * rsqrtf(b2v[t] + eps);
            o[O_B2_S + t] = s; o[O_B2_B + t] = b2b[t] - b2m[t] * s;
        }
        if (t < 128) {
            float s = e1g[t] * rsqrtf(e1v[t] + eps);
            o[O_E1_S + t] = s; o[O_E1_B + t] = e1b[t] - e1m[t] * s;
            s = s1g[t] * rsqrtf(s1v[t] + eps);
            o[O_S1_S + t] = s; o[O_S1_B + t] = s1bb[t] - s1m[t] * s;
        }
        for (int i = t; i < 288; i += 256) o[O_E2B + i] = e2b[i];
    } else {                                // zeros: gnsum (1024) + gap (4096)
        int j = (bid - 1233) * 256 + t;
        if (j < 1024) o[O_GNS + j] = 0.f;
        else          o[O_GAP + j - 1024] = 0.f;
    }
}

// ================= x: fp32 NCHW -> bf16 NHWC via LDS transpose =================
__global__ __launch_bounds__(256) void cvt_x(const float* __restrict__ x, bf16* __restrict__ xh)
{
    int b = blockIdx.y;
    int p0 = blockIdx.x * 64;
    __shared__ bf16 T[64][264];
    int t = threadIdx.x;
    for (int it = 0; it < 16; it++) {
        int slot = t + it * 256;
        int c = slot >> 4, ch4 = slot & 15;
        float4 v = *(const float4*)(x + ((long)b * CDIM + c) * NPIX + p0 + ch4 * 4);
        T[ch4 * 4 + 0][c] = f2b(v.x);
        T[ch4 * 4 + 1][c] = f2b(v.y);
        T[ch4 * 4 + 2][c] = f2b(v.z);
        T[ch4 * 4 + 3][c] = f2b(v.w);
    }
    __syncthreads();
    for (int it = 0; it < 8; it++) {
        int slot = t + it * 256;
        int p = slot >> 5, cc = slot & 31;
        *(float4*)(xh + ((long)b * NPIX + p0 + p) * CDIM + cc * 8) = *(const float4*)&T[p][cc * 8];
    }
}

// ================= grouped 3x3 conv: halo-LDS, barrier-free MFMA loop ==========
// grid (49, 4, 16) = (pixel tile, group, batch), block 256 (4 waves, co-split)
__global__ __launch_bounds__(256) void gconv_mfma(
    const bf16* __restrict__ xh, const bf16* __restrict__ wT,
    const float* __restrict__ scale, const float* __restrict__ bias,
    bf16* __restrict__ kh)
{
    int b = blockIdx.z, g = blockIdx.y;
    int p0 = blockIdx.x * 64;
    __shared__ bf16 As[5 * 58 * 72];       // 5 halo rows x 58 cols x 64ch (pad 72)
    int t = threadIdx.x;
    int wv = t >> 6, lane = t & 63, q = lane >> 4, ln = lane & 15;
    int r_first = p0 / HDIM - 1;

    // ---- stage halo once: 290 positions x 8 chunks(16B) = 2320 slots ----
    #pragma unroll
    for (int i = 0; i < 10; i++) {
        int slot = t + i * 256;
        if (slot < 2320) {
            int chunk = slot & 7, pos = slot >> 3;
            int ri = pos / 58, ci = pos - ri * 58;
            int h = r_first + ri, w = ci - 1;
            float4 v = {0.f, 0.f, 0.f, 0.f};
            if ((unsigned)h < HDIM && (unsigned)w < HDIM)
                v = *(const float4*)(xh + ((long)b * NPIX + h * HDIM + w) * CDIM + g * 64 + chunk * 8);
            *(float4*)&As[pos * 72 + chunk * 8] = v;
        }
    }
    __syncthreads();

    // per-lane pixel positions for the 4 px-subtiles
    int posp[4];
    #pragma unroll
    for (int pt = 0; pt < 4; pt++) {
        int p = p0 + pt * 16 + ln;
        int hp = p / HDIM, wp = p - hp * HDIM;
        posp[pt] = (hp - r_first) * 58 + wp + 1;
    }
    const bf16* wbase = wT + ((long)(g * 9) * 64 + wv * 16 + ln) * 64;

    f32x4 acc[4] = {};
    #pragma unroll
    for (int tap = 0; tap < 9; tap++) {
        int dpos = (tap / 3 - 1) * 58 + (tap % 3 - 1);
        const bf16* wp = wbase + tap * 64 * 64;
        s16x8 B0 = *(const s16x8*)(wp + q * 8);
        s16x8 B1 = *(const s16x8*)(wp + 32 + q * 8);
        #pragma unroll
        for (int pt = 0; pt < 4; pt++) {
            int base = (posp[pt] + dpos) * 72 + q * 8;
            s16x8 a0 = *(const s16x8*)&As[base];
            s16x8 a1 = *(const s16x8*)&As[base + 32];
            acc[pt] = __builtin_amdgcn_mfma_f32_16x16x32_bf16(a0, B0, acc[pt], 0, 0, 0);
            acc[pt] = __builtin_amdgcn_mfma_f32_16x16x32_bf16(a1, B1, acc[pt], 0, 0, 0);
        }
    }

    // ---- epilogue: BN+ReLU, transpose via LDS, coalesced store ----
    __syncthreads();
    int co = g * 64 + wv * 16 + ln;
    float sc = scale[co], bi = bias[co];
    #pragma unroll
    for (int pt = 0; pt < 4; pt++)
        #pragma unroll
        for (int r = 0; r < 4; r++)
            As[(pt * 16 + q * 4 + r) * 72 + wv * 16 + ln] = f2b(fmaxf(acc[pt][r] * sc + bi, 0.f));
    __syncthreads();
    #pragma unroll
    for (int i = 0; i < 2; i++) {
        int slot = t + i * 256;
        int row = slot >> 3, cc = slot & 7;
        *(float4*)(kh + ((long)b * NPIX + p0 + row) * CDIM + g * 64 + cc * 8) = *(const float4*)&As[row * 72 + cc * 8];
    }
}

// ================= 1x1 conv GEMM: direct-frag global loads, no staging LDS =====
// MODE 0: BN+ReLU   MODE 1: +bias + fused GN partial sums   MODE 2: BN only
// grid (49, ceil(M/64), 16), block 256
template<int MODE>
__global__ __launch_bounds__(256) void mfma_gemm(
    const bf16* __restrict__ Wt, const bf16* __restrict__ X0, const bf16* __restrict__ X1,
    int C0, int K, int M,
    const float* __restrict__ scale, const float* __restrict__ bias,
    bf16* __restrict__ Y, float* __restrict__ gnsum)
{
    int b = blockIdx.z;
    int p0 = blockIdx.x * 64;
    int m0 = blockIdx.y * 64;
    __shared__ bf16 T[64 * 72];
    __shared__ float gs[64];
    int t = threadIdx.x;
    int wv = t >> 6, lane = t & 63, q = lane >> 4, ln = lane & 15;
    if (MODE == 1) { if (t < 64) gs[t] = 0.f; __syncthreads(); }

    int px = p0 + wv * 16 + ln;
    const bf16* pA0 = X0 + ((long)b * NPIX + px) * C0;
    const bf16* pA1 = X1 ? X1 + ((long)b * NPIX + px) * (K - C0) : nullptr;
    const bf16* pB[4];
    #pragma unroll
    for (int s = 0; s < 4; s++) {
        int m = m0 + s * 16 + ln; if (m > M - 1) m = M - 1;
        pB[s] = Wt + (long)m * K;
    }

    f32x4 acc[4] = {};
    for (int k0 = 0; k0 < K; k0 += 64) {
        const bf16* pa = (k0 < C0) ? (pA0 + k0) : (pA1 + (k0 - C0));
        s16x8 a0 = *(const s16x8*)(pa + q * 8);
        s16x8 a1 = *(const s16x8*)(pa + 32 + q * 8);
        #pragma unroll
        for (int s = 0; s < 4; s++) {
            s16x8 b0 = *(const s16x8*)(pB[s] + k0 + q * 8);
            s16x8 b1 = *(const s16x8*)(pB[s] + k0 + 32 + q * 8);
            acc[s] = __builtin_amdgcn_mfma_f32_16x16x32_bf16(a0, b0, acc[s], 0, 0, 0);
            acc[s] = __builtin_amdgcn_mfma_f32_16x16x32_bf16(a1, b1, acc[s], 0, 0, 0);
        }
    }

    // ---- epilogue ----
    #pragma unroll
    for (int s = 0; s < 4; s++) {
        int m = m0 + s * 16 + ln;
        int mc = (m > M - 1) ? (M - 1) : m;
        float sc = 1.f, bi;
        if (MODE == 0 || MODE == 2) { sc = scale[mc]; bi = bias[mc]; }
        else bi = bias[mc];
        float ps = 0.f, pq = 0.f;
        #pragma unroll
        for (int r = 0; r < 4; r++) {
            float v = acc[s][r] * sc + bi;
            if (MODE == 0) v = fmaxf(v, 0.f);
            if (MODE == 1) { ps += v; pq += v * v; }
            T[(wv * 16 + q * 4 + r) * 72 + s * 16 + ln] = f2b(v);
        }
        if (MODE == 1 && m < M) {
            int grp = m / 9;
            atomicAdd(&gs[grp * 2], ps);
            atomicAdd(&gs[grp * 2 + 1], pq);
        }
    }
    __syncthreads();
    #pragma unroll
    for (int i = 0; i < 2; i++) {
        int slot = t + i * 256;
        int row = slot >> 3, cc = slot & 7;
        if (m0 + cc * 8 + 8 <= M)
            *(float4*)(Y + ((long)b * NPIX + p0 + row) * M + m0 + cc * 8) = *(const float4*)&T[row * 72 + cc * 8];
    }
    if (MODE == 1 && t < 64) atomicAdd(&gnsum[b * 64 + t], gs[t]);
}

// ================= dynamic local conv + inline GN + BN(b2) + swish =============
__global__ __launch_bounds__(256) void dynconv(
    const bf16* __restrict__ xq, const bf16* __restrict__ wemb,
    const float* __restrict__ gnsum,
    const float* __restrict__ gng, const float* __restrict__ gnb,
    const float* __restrict__ b2s, const float* __restrict__ b2b,
    bf16* __restrict__ y)
{
    int id = blockIdx.x * 256 + threadIdx.x;
    int grp = id & 31;
    int p = (id >> 5) % NPIX;
    int b = id / (NPIX * 32);
    int h = p / HDIM, w = p % HDIM;
    float S = gnsum[b * 64 + grp * 2], Q = gnsum[b * 64 + grp * 2 + 1];
    float mu = S * (1.f / 28224.f);
    float var = Q * (1.f / 28224.f) - mu * mu;
    float rs = rsqrtf(fmaxf(var, 0.f) + 1e-5f);
    const bf16* wp = wemb + ((long)b * NPIX + p) * 288 + grp * 9;
    float wv[9];
    #pragma unroll
    for (int tp = 0; tp < 9; tp++)
        wv[tp] = (b2f(wp[tp]) - mu) * rs * gng[grp * 9 + tp] + gnb[grp * 9 + tp];
    float acc[8] = {};
    #pragma unroll
    for (int tp = 0; tp < 9; tp++) {
        int h2 = h + tp / 3 - 1, w2 = w + tp % 3 - 1;
        if ((unsigned)h2 >= HDIM || (unsigned)w2 >= HDIM) continue;
        const bf16* xp = xq + ((long)b * NPIX + h2 * HDIM + w2) * CDIM + grp * 8;
        s16x8 xv = *(const s16x8*)xp;
        const bf16* xb = (const bf16*)&xv;
        float wt = wv[tp];
        #pragma unroll
        for (int i = 0; i < 8; i++) acc[i] += b2f(xb[i]) * wt;
    }
    bf16 outv[8];
    #pragma unroll
    for (int i = 0; i < 8; i++) {
        int c = grp * 8 + i;
        float v = acc[i] * b2s[c] + b2b[c];
        outv[i] = f2b(v / (1.f + __expf(-v)));
    }
    *(float4*)(y + ((long)b * NPIX + p) * CDIM + grp * 8) = *(const float4*)outv;
}

// ================= GAP over (y + k) ===========================================
__global__ void gapk(const bf16* __restrict__ y, const bf16* __restrict__ k, float* __restrict__ gap)
{
    int b = blockIdx.x, chunk = blockIdx.y, c = threadIdx.x;
    float s = 0.f;
    for (int i = 0; i < 64; i++) {
        long off = ((long)b * NPIX + chunk * 64 + i) * CDIM + c;
        s += b2f(y[off]) + b2f(k[off]);
    }
    atomicAdd(&gap[b * 256 + c], s * (1.f / NPIX));
}

// ================= split attention ============================================
__global__ void attnk(const float* __restrict__ gap,
                      const float* __restrict__ s1w, const float* __restrict__ s1b,
                      const float* __restrict__ s1s, const float* __restrict__ s1bi,
                      const float* __restrict__ s2w, const float* __restrict__ s2b,
                      float* __restrict__ att)
{
    int b = blockIdx.x, t = threadIdx.x;   // 128 threads
    __shared__ float g[256], a1[128];
    for (int i = t; i < 256; i += 128) g[i] = gap[b * 256 + i];
    __syncthreads();
    float s = 0.f;
    for (int ci = 0; ci < 256; ci++) s += s1w[t * 256 + ci] * g[ci];
    s += s1b[t];
    s = s * s1s[t] + s1bi[t];
    a1[t] = fmaxf(s, 0.f);
    __syncthreads();
    for (int c = t; c < 256; c += 128) {
        float v0 = s2b[2 * c], v1 = s2b[2 * c + 1];
        for (int ci = 0; ci < 128; ci++) {
            float av = a1[ci];
            v0 += s2w[(2 * c) * 128 + ci] * av;
            v1 += s2w[(2 * c + 1) * 128 + ci] * av;
        }
        float m = fmaxf(v0, v1);
        float e0 = __expf(v0 - m), e1 = __expf(v1 - m);
        float inv = 1.f / (e0 + e1);
        att[(b * 256 + c) * 2 + 0] = e0 * inv;
        att[(b * 256 + c) * 2 + 1] = e1 * inv;
    }
}

// ================= final: combine + NHWC->NCHW fp32 out =======================
__global__ __launch_bounds__(256) void finalk(
    const bf16* __restrict__ y, const bf16* __restrict__ k,
    const float* __restrict__ att, float* __restrict__ out)
{
    int b = blockIdx.z, c0 = blockIdx.y * 64, p0 = blockIdx.x * 64;
    __shared__ bf16 Ys[64][72], Ks[64][72];
    int t = threadIdx.x;
    #pragma unroll
    for (int i = 0; i < 2; i++) {
        int slot = t + i * 256;
        int row = slot >> 3, cc = slot & 7;
        long off = ((long)b * NPIX + p0 + row) * CDIM + c0 + cc * 8;
        *(float4*)&Ys[row][cc * 8] = *(const float4*)(y + off);
        *(float4*)&Ks[row][cc * 8] = *(const float4*)(k + off);
    }
    __syncthreads();
    int c_l = t >> 2, pc = t & 3;
    int c = c0 + c_l;
    float a0 = att[(b * 256 + c) * 2], a1 = att[(b * 256 + c) * 2 + 1];
    float4 o[4];
    float* of = (float*)o;
    #pragma unroll
    for (int j = 0; j < 16; j++) {
        int p = pc * 16 + j;
        of[j] = b2f(Ys[p][c_l]) * a0 + b2f(Ks[p][c_l]) * a1;
    }
    float* dst = out + ((long)b * CDIM + c) * NPIX + p0 + pc * 16;
    #pragma unroll
    for (int j = 0; j < 4; j++) ((float4*)dst)[j] = o[j];
}

extern "C" void kernel_launch(void* const* d_in, const int* in_sizes, int n_in,
                              void* d_out, int out_size, void* d_ws, size_t ws_size,
                              hipStream_t stream)
{
    const float* x    = (const float*)d_in[0];
    const float* ke_w = (const float*)d_in[1];
    const float* ke_g = (const float*)d_in[2];
    const float* ke_b = (const float*)d_in[3];
    const float* ke_m = (const float*)d_in[4];
    const float* ke_v = (const float*)d_in[5];
    const float* e1_w = (const float*)d_in[6];
    const float* e1_g = (const float*)d_in[7];
    const float* e1_b = (const float*)d_in[8];
    const float* e1_m = (const float*)d_in[9];
    const float* e1_v = (const float*)d_in[10];
    const float* e2_w = (const float*)d_in[11];
    const float* e2_b = (const float*)d_in[12];
    const float* gng  = (const float*)d_in[13];
    const float* gnb  = (const float*)d_in[14];
    const float* c1_w = (const float*)d_in[15];
    const float* c1_g = (const float*)d_in[16];
    const float* c1_b = (const float*)d_in[17];
    const float* c1_m = (const float*)d_in[18];
    const float* c1_v = (const float*)d_in[19];
    const float* b2_g = (const float*)d_in[20];
    const float* b2_b = (const float*)d_in[21];
    const float* b2_m = (const float*)d_in[22];
    const float* b2_v = (const float*)d_in[23];
    const float* s1_w = (const float*)d_in[24];
    const float* s1_b = (const float*)d_in[25];
    const float* s1_g = (const float*)d_in[26];
    const float* s1_bb= (const float*)d_in[27];
    const float* s1_m = (const float*)d_in[28];
    const float* s1_v = (const float*)d_in[29];
    const float* s2_w = (const float*)d_in[30];
    const float* s2_b = (const float*)d_in[31];

    float* fold = (float*)d_ws;
    bf16* wsb   = (bf16*)((char*)d_ws + 65536);
    bf16* xh   = wsb;                     // 12,845,056  (aliased by yb after c1)
    bf16* kh   = xh + 12845056L;          // 12,845,056
    bf16* wemb = kh + 12845056L;          // 14,450,688
    bf16* w1   = wemb + 14450688L;        // region 12,845,056 (w1 6.4M, then xq)
    bf16* xq   = w1;                      // alias (w1 dead before c1)
    bf16* yb   = xh;                      // alias (xh dead before dynconv)
    bf16* kewT = w1 + 12845056L;          // 147,456
    bf16* e1wb = kewT + 147456L;          // 65,536
    bf16* e2wb = e1wb + 65536L;           // 36,864
    bf16* c1wb = e2wb + 36864L;           // 65,536

    prep<<<dim3(1253), dim3(256), 0, stream>>>(
        ke_w, e1_w, e2_w, c1_w,
        ke_g, ke_b, ke_m, ke_v, e1_g, e1_b, e1_m, e1_v, e2_b,
        c1_g, c1_b, c1_m, c1_v, b2_g, b2_b, b2_m, b2_v,
        s1_g, s1_bb, s1_m, s1_v,
        kewT, e1wb, e2wb, c1wb, fold);

    cvt_x<<<dim3(49, 16), dim3(256), 0, stream>>>(x, xh);

    gconv_mfma<<<dim3(49, 4, 16), dim3(256), 0, stream>>>(
        xh, kewT, fold + O_KE_S, fold + O_KE_B, kh);

    mfma_gemm<0><<<dim3(49, 2, 16), dim3(256), 0, stream>>>(
        e1wb, xh, kh, 256, 512, 128, fold + O_E1_S, fold + O_E1_B, w1, nullptr);

    mfma_gemm<1><<<dim3(49, 5, 16), dim3(256), 0, stream>>>(
        e2wb, w1, (const bf16*)nullptr, 128, 128, 288, (const float*)nullptr, fold + O_E2B,
        wemb, fold + O_GNS);

    mfma_gemm<2><<<dim3(49, 4, 16), dim3(256), 0, stream>>>(
        c1wb, xh, (const bf16*)nullptr, 256, 256, 256, fold + O_C1_S, fold + O_C1_B, xq, nullptr);

    dynconv<<<dim3(6272), dim3(256), 0, stream>>>(
        xq, wemb, fold + O_GNS, gng, gnb,
        fold + O_B2_S, fold + O_B2_B, yb);

    gapk<<<dim3(16, 49), dim3(256), 0, stream>>>(yb, kh, fold + O_GAP);

    attnk<<<dim3(16), dim3(128), 0, stream>>>(
        fold + O_GAP, s1_w, s1_b, fold + O_S1_S, fold + O_S1_B, s2_w, s2_b, fold + O_ATT);

    finalk<<<dim3(49, 4, 16), dim3(256), 0, stream>>>(yb, kh, fold + O_ATT, (float*)d_out);
}

// Round 5
// 366.629 us; speedup vs baseline: 1.3600x; 1.3600x over previous
//
#include <hip/hip_runtime.h>
#include <hip/hip_bf16.h>

typedef __hip_bfloat16 bf16;
typedef float f32x4 __attribute__((ext_vector_type(4)));
typedef short s16x8 __attribute__((ext_vector_type(8)));

#define NPIX 3136   // 56*56
#define HDIM 56
#define CDIM 256

static __device__ __forceinline__ float b2f(bf16 v){ return __bfloat162float(v); }
static __device__ __forceinline__ bf16  f2b(float v){ return __float2bfloat16(v); }

// ---- fold region float offsets ----
#define O_KE_S 0
#define O_KE_B 256
#define O_E1_S 512
#define O_E1_B 640
#define O_C1_S 768
#define O_C1_B 1024
#define O_B2_S 1280
#define O_B2_B 1536
#define O_S1_S 1792
#define O_S1_B 1920
#define O_E2B  2048
#define O_GNS  2336   // gnsum[b][grp][2] : 16*32*2 = 1024 floats
#define O_GAP  3360
#define O_ATT  7456

// ================= prep: weight converts + BN folds + zeros, one kernel =========
__global__ void prep(
    const float* __restrict__ kew, const float* __restrict__ e1w,
    const float* __restrict__ e2w, const float* __restrict__ c1w,
    const float* keg, const float* keb, const float* kem, const float* kev,
    const float* e1g, const float* e1b, const float* e1m, const float* e1v,
    const float* e2b,
    const float* c1g, const float* c1b, const float* c1m, const float* c1v,
    const float* b2g, const float* b2b, const float* b2m, const float* b2v,
    const float* s1g, const float* s1bb, const float* s1m, const float* s1v,
    bf16* kewT, bf16* e1wb, bf16* e2wb, bf16* c1wb, float* o)
{
    int bid = blockIdx.x, t = threadIdx.x;
    if (bid < 576) {                       // kewT: (256,64,3,3) -> [g][tap][co_l][ci]
        int i = bid * 256 + t;
        int ci = i & 63, co_l = (i >> 6) & 63;
        int gt = i >> 12;
        int tap = gt % 9, g = gt / 9;
        int co = g * 64 + co_l;
        kewT[i] = f2b(kew[(co * 64 + ci) * 9 + tap]);
    } else if (bid < 832) {
        int i = (bid - 576) * 256 + t; e1wb[i] = f2b(e1w[i]);
    } else if (bid < 976) {
        int i = (bid - 832) * 256 + t; e2wb[i] = f2b(e2w[i]);
    } else if (bid < 1232) {
        int i = (bid - 976) * 256 + t; c1wb[i] = f2b(c1w[i]);
    } else if (bid == 1232) {
        const float eps = 1e-5f;
        {
            float s = keg[t] * rsqrtf(kev[t] + eps);
            o[O_KE_S + t] = s; o[O_KE_B + t] = keb[t] - kem[t] * s;
            s = c1g[t] * rsqrtf(c1v[t] + eps);
            o[O_C1_S + t] = s; o[O_C1_B + t] = c1b[t] - c1m[t] * s;
            s = b2g[t] * rsqrtf(b2v[t] + eps);
            o[O_B2_S + t] = s; o[O_B2_B + t] = b2b[t] - b2m[t] * s;
        }
        if (t < 128) {
            float s = e1g[t] * rsqrtf(e1v[t] + eps);
            o[O_E1_S + t] = s; o[O_E1_B + t] = e1b[t] - e1m[t] * s;
            s = s1g[t] * rsqrtf(s1v[t] + eps);
            o[O_S1_S + t] = s; o[O_S1_B + t] = s1bb[t] - s1m[t] * s;
        }
        for (int i = t; i < 288; i += 256) o[O_E2B + i] = e2b[i];
    } else {                                // zeros: gnsum (1024) + gap (4096)
        int j = (bid - 1233) * 256 + t;
        if (j < 1024) o[O_GNS + j] = 0.f;
        else          o[O_GAP + j - 1024] = 0.f;
    }
}

// ================= x: fp32 NCHW -> bf16 NHWC via LDS transpose =================
__global__ __launch_bounds__(256) void cvt_x(const float* __restrict__ x, bf16* __restrict__ xh)
{
    int b = blockIdx.y;
    int p0 = blockIdx.x * 64;
    __shared__ bf16 T[64][264];
    int t = threadIdx.x;
    for (int it = 0; it < 16; it++) {
        int slot = t + it * 256;
        int c = slot >> 4, ch4 = slot & 15;
        float4 v = *(const float4*)(x + ((long)b * CDIM + c) * NPIX + p0 + ch4 * 4);
        T[ch4 * 4 + 0][c] = f2b(v.x);
        T[ch4 * 4 + 1][c] = f2b(v.y);
        T[ch4 * 4 + 2][c] = f2b(v.z);
        T[ch4 * 4 + 3][c] = f2b(v.w);
    }
    __syncthreads();
    for (int it = 0; it < 8; it++) {
        int slot = t + it * 256;
        int p = slot >> 5, cc = slot & 31;
        *(float4*)(xh + ((long)b * NPIX + p0 + p) * CDIM + cc * 8) = *(const float4*)&T[p][cc * 8];
    }
}

// ================= grouped 3x3 conv: halo-LDS, barrier-free MFMA loop ==========
// grid (49, 4, 16) = (pixel tile, group, batch), block 256 (4 waves, co-split)
__global__ __launch_bounds__(256) void gconv_mfma(
    const bf16* __restrict__ xh, const bf16* __restrict__ wT,
    const float* __restrict__ scale, const float* __restrict__ bias,
    bf16* __restrict__ kh)
{
    int b = blockIdx.z, g = blockIdx.y;
    int p0 = blockIdx.x * 64;
    __shared__ bf16 As[5 * 58 * 72];       // 5 halo rows x 58 cols x 64ch (pad 72)
    int t = threadIdx.x;
    int wv = t >> 6, lane = t & 63, q = lane >> 4, ln = lane & 15;
    int r_first = p0 / HDIM - 1;

    // ---- stage halo once: 290 positions x 8 chunks(16B) = 2320 slots ----
    #pragma unroll
    for (int i = 0; i < 10; i++) {
        int slot = t + i * 256;
        if (slot < 2320) {
            int chunk = slot & 7, pos = slot >> 3;
            int ri = pos / 58, ci = pos - ri * 58;
            int h = r_first + ri, w = ci - 1;
            float4 v = {0.f, 0.f, 0.f, 0.f};
            if ((unsigned)h < HDIM && (unsigned)w < HDIM)
                v = *(const float4*)(xh + ((long)b * NPIX + h * HDIM + w) * CDIM + g * 64 + chunk * 8);
            *(float4*)&As[pos * 72 + chunk * 8] = v;
        }
    }
    __syncthreads();

    // per-lane pixel positions for the 4 px-subtiles
    int posp[4];
    #pragma unroll
    for (int pt = 0; pt < 4; pt++) {
        int p = p0 + pt * 16 + ln;
        int hp = p / HDIM, wp = p - hp * HDIM;
        posp[pt] = (hp - r_first) * 58 + wp + 1;
    }
    const bf16* wbase = wT + ((long)(g * 9) * 64 + wv * 16 + ln) * 64;

    f32x4 acc[4] = {};
    #pragma unroll
    for (int tap = 0; tap < 9; tap++) {
        int dpos = (tap / 3 - 1) * 58 + (tap % 3 - 1);
        const bf16* wp = wbase + tap * 64 * 64;
        s16x8 B0 = *(const s16x8*)(wp + q * 8);
        s16x8 B1 = *(const s16x8*)(wp + 32 + q * 8);
        #pragma unroll
        for (int pt = 0; pt < 4; pt++) {
            int base = (posp[pt] + dpos) * 72 + q * 8;
            s16x8 a0 = *(const s16x8*)&As[base];
            s16x8 a1 = *(const s16x8*)&As[base + 32];
            acc[pt] = __builtin_amdgcn_mfma_f32_16x16x32_bf16(a0, B0, acc[pt], 0, 0, 0);
            acc[pt] = __builtin_amdgcn_mfma_f32_16x16x32_bf16(a1, B1, acc[pt], 0, 0, 0);
        }
    }

    // ---- epilogue: BN+ReLU, transpose via LDS, coalesced store ----
    __syncthreads();
    int co = g * 64 + wv * 16 + ln;
    float sc = scale[co], bi = bias[co];
    #pragma unroll
    for (int pt = 0; pt < 4; pt++)
        #pragma unroll
        for (int r = 0; r < 4; r++)
            As[(pt * 16 + q * 4 + r) * 72 + wv * 16 + ln] = f2b(fmaxf(acc[pt][r] * sc + bi, 0.f));
    __syncthreads();
    #pragma unroll
    for (int i = 0; i < 2; i++) {
        int slot = t + i * 256;
        int row = slot >> 3, cc = slot & 7;
        *(float4*)(kh + ((long)b * NPIX + p0 + row) * CDIM + g * 64 + cc * 8) = *(const float4*)&As[row * 72 + cc * 8];
    }
}

// ================= 1x1 conv GEMM: LDS-staged, 64px x 128m tile, BK=64 ==========
// MODE 0: BN+ReLU   MODE 1: +bias + fused GN partial sums   MODE 2: BN only
// grid (49, ceil(M/128), 16), block 256 (4 waves)
template<int MODE>
__global__ __launch_bounds__(256) void mfma_gemm(
    const bf16* __restrict__ Wt, const bf16* __restrict__ X0, const bf16* __restrict__ X1,
    int C0, int K, int M,
    const float* __restrict__ scale, const float* __restrict__ bias,
    bf16* __restrict__ Y, float* __restrict__ gnsum)
{
    int b = blockIdx.z;
    int p0 = blockIdx.x * 64;
    int m0 = blockIdx.y * 128;
    __shared__ bf16 SH[64 * 72 + 128 * 72];   // As | Bs ; epilogue T (64x144) aliases
    bf16* As = SH;
    bf16* Bs = SH + 64 * 72;
    __shared__ float gs[64];
    int t = threadIdx.x;
    int wv = t >> 6, lane = t & 63, q = lane >> 4, ln = lane & 15;
    if (MODE == 1) { if (t < 64) gs[t] = 0.f; }

    f32x4 acc[4][2] = {};
    for (int k0 = 0; k0 < K; k0 += 64) {
        __syncthreads();
        // stage A: 64 rows x 8 chunks of 16B (coalesced 128B per 8 threads)
        #pragma unroll
        for (int i = 0; i < 2; i++) {
            int slot = t + i * 256;
            int chunk = slot & 7, row = slot >> 3;
            int ch = k0 + chunk * 8;
            const bf16* src = (ch < C0)
                ? X0 + ((long)b * NPIX + p0 + row) * C0 + ch
                : X1 + ((long)b * NPIX + p0 + row) * (K - C0) + (ch - C0);
            *(float4*)&As[row * 72 + chunk * 8] = *(const float4*)src;
        }
        // stage B: 128 rows x 8 chunks
        #pragma unroll
        for (int i = 0; i < 4; i++) {
            int slot = t + i * 256;
            int chunk = slot & 7, row = slot >> 3;
            int m = m0 + row;
            float4 v = {0.f, 0.f, 0.f, 0.f};
            if (m < M) v = *(const float4*)(Wt + (long)m * K + k0 + chunk * 8);
            *(float4*)&Bs[row * 72 + chunk * 8] = v;
        }
        __syncthreads();
        #pragma unroll
        for (int kk = 0; kk < 2; kk++) {
            s16x8 a[4];
            #pragma unroll
            for (int pt = 0; pt < 4; pt++)
                a[pt] = *(const s16x8*)&As[(pt * 16 + ln) * 72 + kk * 32 + q * 8];
            #pragma unroll
            for (int mi = 0; mi < 2; mi++) {
                s16x8 bb = *(const s16x8*)&Bs[(wv * 32 + mi * 16 + ln) * 72 + kk * 32 + q * 8];
                #pragma unroll
                for (int pt = 0; pt < 4; pt++)
                    acc[pt][mi] = __builtin_amdgcn_mfma_f32_16x16x32_bf16(a[pt], bb, acc[pt][mi], 0, 0, 0);
            }
        }
    }

    // ---- epilogue: scale/bias (+GN partials), LDS transpose, coalesced store ----
    __syncthreads();
    bf16* T = SH;                     // 64 x 144 (rows 288B, 16B-aligned)
    #pragma unroll
    for (int mi = 0; mi < 2; mi++) {
        int m = m0 + wv * 32 + mi * 16 + ln;
        int mc = (m > M - 1) ? (M - 1) : m;
        float sc = 1.f, bi;
        if (MODE == 0 || MODE == 2) { sc = scale[mc]; bi = bias[mc]; }
        else bi = bias[mc];
        float ps = 0.f, pq = 0.f;
        #pragma unroll
        for (int pt = 0; pt < 4; pt++) {
            #pragma unroll
            for (int r = 0; r < 4; r++) {
                float v = acc[pt][mi][r] * sc + bi;
                if (MODE == 0) v = fmaxf(v, 0.f);
                if (MODE == 1) { ps += v; pq += v * v; }
                T[(pt * 16 + q * 4 + r) * 144 + wv * 32 + mi * 16 + ln] = f2b(v);
            }
        }
        if (MODE == 1 && m < M) {
            int grp = m / 9;
            atomicAdd(&gs[grp * 2], ps);
            atomicAdd(&gs[grp * 2 + 1], pq);
        }
    }
    __syncthreads();
    #pragma unroll
    for (int i = 0; i < 4; i++) {
        int slot = t + i * 256;
        int chunk = slot & 15, row = slot >> 4;
        int m = m0 + chunk * 8;
        if (m + 8 <= M)
            *(float4*)(Y + ((long)b * NPIX + p0 + row) * M + m) = *(const float4*)&T[row * 144 + chunk * 8];
    }
    if (MODE == 1 && t < 64) atomicAdd(&gnsum[b * 64 + t], gs[t]);
}

// ================= dynamic local conv + inline GN + BN(b2) + swish =============
__global__ __launch_bounds__(256) void dynconv(
    const bf16* __restrict__ xq, const bf16* __restrict__ wemb,
    const float* __restrict__ gnsum,
    const float* __restrict__ gng, const float* __restrict__ gnb,
    const float* __restrict__ b2s, const float* __restrict__ b2b,
    bf16* __restrict__ y)
{
    int id = blockIdx.x * 256 + threadIdx.x;
    int grp = id & 31;
    int p = (id >> 5) % NPIX;
    int b = id / (NPIX * 32);
    int h = p / HDIM, w = p % HDIM;
    float S = gnsum[b * 64 + grp * 2], Q = gnsum[b * 64 + grp * 2 + 1];
    float mu = S * (1.f / 28224.f);
    float var = Q * (1.f / 28224.f) - mu * mu;
    float rs = rsqrtf(fmaxf(var, 0.f) + 1e-5f);
    const bf16* wp = wemb + ((long)b * NPIX + p) * 288 + grp * 9;
    float wv[9];
    #pragma unroll
    for (int tp = 0; tp < 9; tp++)
        wv[tp] = (b2f(wp[tp]) - mu) * rs * gng[grp * 9 + tp] + gnb[grp * 9 + tp];
    float acc[8] = {};
    #pragma unroll
    for (int tp = 0; tp < 9; tp++) {
        int h2 = h + tp / 3 - 1, w2 = w + tp % 3 - 1;
        if ((unsigned)h2 >= HDIM || (unsigned)w2 >= HDIM) continue;
        const bf16* xp = xq + ((long)b * NPIX + h2 * HDIM + w2) * CDIM + grp * 8;
        s16x8 xv = *(const s16x8*)xp;
        const bf16* xb = (const bf16*)&xv;
        float wt = wv[tp];
        #pragma unroll
        for (int i = 0; i < 8; i++) acc[i] += b2f(xb[i]) * wt;
    }
    bf16 outv[8];
    #pragma unroll
    for (int i = 0; i < 8; i++) {
        int c = grp * 8 + i;
        float v = acc[i] * b2s[c] + b2b[c];
        outv[i] = f2b(v / (1.f + __expf(-v)));
    }
    *(float4*)(y + ((long)b * NPIX + p) * CDIM + grp * 8) = *(const float4*)outv;
}

// ================= GAP over (y + k) ===========================================
__global__ void gapk(const bf16* __restrict__ y, const bf16* __restrict__ k, float* __restrict__ gap)
{
    int b = blockIdx.x, chunk = blockIdx.y, c = threadIdx.x;
    float s = 0.f;
    for (int i = 0; i < 64; i++) {
        long off = ((long)b * NPIX + chunk * 64 + i) * CDIM + c;
        s += b2f(y[off]) + b2f(k[off]);
    }
    atomicAdd(&gap[b * 256 + c], s * (1.f / NPIX));
}

// ================= split attention ============================================
__global__ void attnk(const float* __restrict__ gap,
                      const float* __restrict__ s1w, const float* __restrict__ s1b,
                      const float* __restrict__ s1s, const float* __restrict__ s1bi,
                      const float* __restrict__ s2w, const float* __restrict__ s2b,
                      float* __restrict__ att)
{
    int b = blockIdx.x, t = threadIdx.x;   // 128 threads
    __shared__ float g[256], a1[128];
    for (int i = t; i < 256; i += 128) g[i] = gap[b * 256 + i];
    __syncthreads();
    float s = 0.f;
    for (int ci = 0; ci < 256; ci++) s += s1w[t * 256 + ci] * g[ci];
    s += s1b[t];
    s = s * s1s[t] + s1bi[t];
    a1[t] = fmaxf(s, 0.f);
    __syncthreads();
    for (int c = t; c < 256; c += 128) {
        float v0 = s2b[2 * c], v1 = s2b[2 * c + 1];
        for (int ci = 0; ci < 128; ci++) {
            float av = a1[ci];
            v0 += s2w[(2 * c) * 128 + ci] * av;
            v1 += s2w[(2 * c + 1) * 128 + ci] * av;
        }
        float m = fmaxf(v0, v1);
        float e0 = __expf(v0 - m), e1 = __expf(v1 - m);
        float inv = 1.f / (e0 + e1);
        att[(b * 256 + c) * 2 + 0] = e0 * inv;
        att[(b * 256 + c) * 2 + 1] = e1 * inv;
    }
}

// ================= final: combine + NHWC->NCHW fp32 out =======================
__global__ __launch_bounds__(256) void finalk(
    const bf16* __restrict__ y, const bf16* __restrict__ k,
    const float* __restrict__ att, float* __restrict__ out)
{
    int b = blockIdx.z, c0 = blockIdx.y * 64, p0 = blockIdx.x * 64;
    __shared__ bf16 Ys[64][72], Ks[64][72];
    int t = threadIdx.x;
    #pragma unroll
    for (int i = 0; i < 2; i++) {
        int slot = t + i * 256;
        int row = slot >> 3, cc = slot & 7;
        long off = ((long)b * NPIX + p0 + row) * CDIM + c0 + cc * 8;
        *(float4*)&Ys[row][cc * 8] = *(const float4*)(y + off);
        *(float4*)&Ks[row][cc * 8] = *(const float4*)(k + off);
    }
    __syncthreads();
    int c_l = t >> 2, pc = t & 3;
    int c = c0 + c_l;
    float a0 = att[(b * 256 + c) * 2], a1 = att[(b * 256 + c) * 2 + 1];
    float4 o[4];
    float* of = (float*)o;
    #pragma unroll
    for (int j = 0; j < 16; j++) {
        int p = pc * 16 + j;
        of[j] = b2f(Ys[p][c_l]) * a0 + b2f(Ks[p][c_l]) * a1;
    }
    float* dst = out + ((long)b * CDIM + c) * NPIX + p0 + pc * 16;
    #pragma unroll
    for (int j = 0; j < 4; j++) ((float4*)dst)[j] = o[j];
}

extern "C" void kernel_launch(void* const* d_in, const int* in_sizes, int n_in,
                              void* d_out, int out_size, void* d_ws, size_t ws_size,
                              hipStream_t stream)
{
    const float* x    = (const float*)d_in[0];
    const float* ke_w = (const float*)d_in[1];
    const float* ke_g = (const float*)d_in[2];
    const float* ke_b = (const float*)d_in[3];
    const float* ke_m = (const float*)d_in[4];
    const float* ke_v = (const float*)d_in[5];
    const float* e1_w = (const float*)d_in[6];
    const float* e1_g = (const float*)d_in[7];
    const float* e1_b = (const float*)d_in[8];
    const float* e1_m = (const float*)d_in[9];
    const float* e1_v = (const float*)d_in[10];
    const float* e2_w = (const float*)d_in[11];
    const float* e2_b = (const float*)d_in[12];
    const float* gng  = (const float*)d_in[13];
    const float* gnb  = (const float*)d_in[14];
    const float* c1_w = (const float*)d_in[15];
    const float* c1_g = (const float*)d_in[16];
    const float* c1_b = (const float*)d_in[17];
    const float* c1_m = (const float*)d_in[18];
    const float* c1_v = (const float*)d_in[19];
    const float* b2_g = (const float*)d_in[20];
    const float* b2_b = (const float*)d_in[21];
    const float* b2_m = (const float*)d_in[22];
    const float* b2_v = (const float*)d_in[23];
    const float* s1_w = (const float*)d_in[24];
    const float* s1_b = (const float*)d_in[25];
    const float* s1_g = (const float*)d_in[26];
    const float* s1_bb= (const float*)d_in[27];
    const float* s1_m = (const float*)d_in[28];
    const float* s1_v = (const float*)d_in[29];
    const float* s2_w = (const float*)d_in[30];
    const float* s2_b = (const float*)d_in[31];

    float* fold = (float*)d_ws;
    bf16* wsb   = (bf16*)((char*)d_ws + 65536);
    bf16* xh   = wsb;                     // 12,845,056  (aliased by yb after c1)
    bf16* kh   = xh + 12845056L;          // 12,845,056
    bf16* wemb = kh + 12845056L;          // 14,450,688
    bf16* w1   = wemb + 14450688L;        // region 12,845,056 (w1 6.4M, then xq)
    bf16* xq   = w1;                      // alias (w1 dead before c1)
    bf16* yb   = xh;                      // alias (xh dead before dynconv)
    bf16* kewT = w1 + 12845056L;          // 147,456
    bf16* e1wb = kewT + 147456L;          // 65,536
    bf16* e2wb = e1wb + 65536L;           // 36,864
    bf16* c1wb = e2wb + 36864L;           // 65,536

    prep<<<dim3(1253), dim3(256), 0, stream>>>(
        ke_w, e1_w, e2_w, c1_w,
        ke_g, ke_b, ke_m, ke_v, e1_g, e1_b, e1_m, e1_v, e2_b,
        c1_g, c1_b, c1_m, c1_v, b2_g, b2_b, b2_m, b2_v,
        s1_g, s1_bb, s1_m, s1_v,
        kewT, e1wb, e2wb, c1wb, fold);

    cvt_x<<<dim3(49, 16), dim3(256), 0, stream>>>(x, xh);

    gconv_mfma<<<dim3(49, 4, 16), dim3(256), 0, stream>>>(
        xh, kewT, fold + O_KE_S, fold + O_KE_B, kh);

    mfma_gemm<0><<<dim3(49, 1, 16), dim3(256), 0, stream>>>(
        e1wb, xh, kh, 256, 512, 128, fold + O_E1_S, fold + O_E1_B, w1, nullptr);

    mfma_gemm<1><<<dim3(49, 3, 16), dim3(256), 0, stream>>>(
        e2wb, w1, (const bf16*)nullptr, 128, 128, 288, (const float*)nullptr, fold + O_E2B,
        wemb, fold + O_GNS);

    mfma_gemm<2><<<dim3(49, 2, 16), dim3(256), 0, stream>>>(
        c1wb, xh, (const bf16*)nullptr, 256, 256, 256, fold + O_C1_S, fold + O_C1_B, xq, nullptr);

    dynconv<<<dim3(6272), dim3(256), 0, stream>>>(
        xq, wemb, fold + O_GNS, gng, gnb,
        fold + O_B2_S, fold + O_B2_B, yb);

    gapk<<<dim3(16, 49), dim3(256), 0, stream>>>(yb, kh, fold + O_GAP);

    attnk<<<dim3(16), dim3(128), 0, stream>>>(
        fold + O_GAP, s1_w, s1_b, fold + O_S1_S, fold + O_S1_B, s2_w, s2_b, fold + O_ATT);

    finalk<<<dim3(49, 4, 16), dim3(256), 0, stream>>>(yb, kh, fold + O_ATT, (float*)d_out);
}